// Round 15
// baseline (152.501 us; speedup 1.0000x reference)
//
#include <hip/hip_runtime.h>
#include <hip/hip_bf16.h>

// SparseAttention B=1,H=8,S=4096,D=32 fp32; mask [S,S] as int32.
// R15: prep_qkv ELIMINATED (R13/R14 ledger: prep_qkv+gap ~58us, invisible to
// top-5). attn consumes raw fp32 Q/K/V: Q converted in-reg once (RNE);
// K/V register-staged per kt (K: contiguous float8; V: 8 scalar loads at
// permuted rows; cvt_pkrtz -> ds_write_b128) into the same proven frag-major
// LDS layout, dbuf + 1 barrier/kt. Reader/compute byte-identical to R12
// (champion, attn 43.8us). prep_mask (~12us, proven) retained.
// No inline asm near MFMA results (R4/R6 lesson).

#define S_  4096
#define D_  32
#define H_  8

typedef _Float16 half8 __attribute__((ext_vector_type(8)));
typedef __fp16 fp16x2 __attribute__((ext_vector_type(2)));
typedef short short8 __attribute__((ext_vector_type(8)));
typedef short short4v __attribute__((ext_vector_type(4)));
typedef float float4v __attribute__((ext_vector_type(4)));
typedef unsigned short ushort_t;
typedef unsigned int u32;

#if __has_builtin(__builtin_amdgcn_exp2f)
#define EXP2(x) __builtin_amdgcn_exp2f(x)
#else
#define EXP2(x) exp2f(x)
#endif

// ---------------- pre-pass: mask repack (proven R12) ----------------
__global__ __launch_bounds__(256)
void prep_mask(const int* __restrict__ mask, ushort_t* __restrict__ mlane)
{
    __shared__ u32 msh[4096];
    const int tid = threadIdx.x;
    const int mb = blockIdx.x;            // [0,1024)
    const int qt16 = mb >> 2, cc = mb & 3;
#pragma unroll
    for (int i = 0; i < 16; ++i) {
        int4 m4 = *(const int4*)(mask + (size_t)(qt16 * 16 + i) * S_ + cc * 1024 + tid * 4);
        u32 v = (m4.x != 0 ? 1u : 0u) | (m4.y != 0 ? 0x100u : 0u)
              | (m4.z != 0 ? 0x10000u : 0u) | (m4.w != 0 ? 0x1000000u : 0u);
        msh[i * 256 + tid] = v;
    }
    __syncthreads();
    const int kt_local = tid >> 4, j = tid & 15;
    const int quad = j >> 2, n2 = j & 3;
    u32 o16[4] = {0, 0, 0, 0};
#pragma unroll
    for (int t16 = 0; t16 < 4; ++t16)
#pragma unroll
        for (int reg = 0; reg < 4; ++reg) {
            u32 v = msh[(quad * 4 + reg) * 256 + kt_local * 16 + t16 * 4 + n2];
            const int bp = t16 * 4 + reg;
            o16[0] |= (v & 1u) << bp;
            o16[1] |= ((v >> 8) & 1u) << bp;
            o16[2] |= ((v >> 16) & 1u) << bp;
            o16[3] |= ((v >> 24) & 1u) << bp;
        }
    union { u32 w[2]; short4v s; } pk;
    pk.w[0] = o16[0] | (o16[1] << 16);
    pk.w[1] = o16[2] | (o16[3] << 16);
    const int kt = cc * 16 + kt_local;
    *(short4v*)(mlane + ((size_t)(qt16 * 64 + kt) * 64 + j * 4)) = pk.s;
}

// ---------------- main kernel: fused convert + MFMA flash ----------------
// 512 thr = 8 waves = 4 wl (q-subtiles of 16) x 2 halves (kt ranges).
// Per kt: each lane register-stages its slice of K (float8, contiguous) and
// V (8 scalar loads, permuted rows), cvt_pkrtz, ds_write_b128 into the
// frag-major dbuf LDS layout (identical to R12's reader layout).

#define PS_STRIDE 72  // fp16 elems; 144B rows

__global__ __launch_bounds__(512, 2)
void attn_mfma(const float* __restrict__ Qf, const float* __restrict__ Kf,
               const float* __restrict__ Vf, const ushort_t* __restrict__ mlane,
               float* __restrict__ out)
{
    // K_s [half][buf][2048] 16KB | V_s same 16KB | Ps 8 waves x 1152 18KB
    __shared__ __align__(16) ushort_t sm[16384 + 8 * 16 * PS_STRIDE];
    ushort_t* K_s  = sm;              // half*4096 + buf*2048 + ...
    ushort_t* Vt_s = sm + 8192;

    const int h  = blockIdx.y;
    const int q0 = blockIdx.x * 64;
    const int tid = threadIdx.x;
    const int w = tid >> 6, l = tid & 63;
    const int half = w >> 2, wl = w & 3;
    const int n16 = l & 15, quad = l >> 4;
    const int khalf = (wl >> 1) & 1, dhalf = wl & 1;   // V-staging decode

    ushort_t* Ps = sm + 16384 + w * 16 * PS_STRIDE;

    const int qt16_u = __builtin_amdgcn_readfirstlane(blockIdx.x * 4 + wl);
    const ushort_t* mlw = mlane + ((size_t)qt16_u << 12);  // [kt][lane]

    // Q: convert in-reg once (RNE), scale*log2e folded
    const int qrow = q0 + wl * 16 + n16;
    const float* qp = Qf + ((size_t)h * S_ + qrow) * D_ + quad * 8;
    const float4 qa = *(const float4*)qp;
    const float4 qb = *(const float4*)(qp + 4);
    const float c = 0.17677669529663687f * 1.4426950408889634f;
    half8 qh;
    qh[0] = (_Float16)(qa.x * c); qh[1] = (_Float16)(qa.y * c);
    qh[2] = (_Float16)(qa.z * c); qh[3] = (_Float16)(qa.w * c);
    qh[4] = (_Float16)(qb.x * c); qh[5] = (_Float16)(qb.y * c);
    qh[6] = (_Float16)(qb.z * c); qh[7] = (_Float16)(qb.w * c);

    half8 ones;
#pragma unroll
    for (int i = 0; i < 8; ++i) ones[i] = (_Float16)1.0f;

    float4v o0 = {0.f, 0.f, 0.f, 0.f};
    float4v o1 = {0.f, 0.f, 0.f, 0.f};
    float4v lacc = {0.f, 0.f, 0.f, 0.f};

    const int hb = half * 4096;
    const int kt_base = half * 32;

    // staging registers for one K/V tile slice
    float4 ka, kb4;
    float vv[8];
    const float* Kh = Kf + (size_t)h * S_ * D_;
    const float* Vh = Vf + (size_t)h * S_ * D_;
    const int vd = dhalf * 16 + n16;

    // ---- load slice of tile kt into regs ----
#define LOAD_TILE(ktv)                                                        \
    {                                                                         \
        const float* kp = Kh + ((size_t)((ktv) * 64 + wl * 16 + n16)) * D_ + quad * 8; \
        ka  = *(const float4*)kp;                                             \
        kb4 = *(const float4*)(kp + 4);                                       \
        _Pragma("unroll")                                                     \
        for (int j = 0; j < 8; ++j) {                                         \
            const int krow = (ktv) * 64 + (j & 3) * 16 + khalf * 8 + quad * 2 + (j >> 2); \
            vv[j] = Vh[(size_t)krow * D_ + vd];                               \
        }                                                                     \
    }

    // ---- cvt + store regs into LDS buffer bufv (frag-major) ----
#define STORE_TILE(bufv)                                                      \
    {                                                                         \
        union { fp16x2 hh[4]; short8 s; } pk;                                 \
        pk.hh[0] = __builtin_amdgcn_cvt_pkrtz(ka.x, ka.y);                    \
        pk.hh[1] = __builtin_amdgcn_cvt_pkrtz(ka.z, ka.w);                    \
        pk.hh[2] = __builtin_amdgcn_cvt_pkrtz(kb4.x, kb4.y);                  \
        pk.hh[3] = __builtin_amdgcn_cvt_pkrtz(kb4.z, kb4.w);                  \
        *(short8*)(K_s + hb + (bufv) * 2048 + wl * 512 + l * 8) = pk.s;       \
        union { fp16x2 hh[4]; short8 s; } pv2;                                \
        pv2.hh[0] = __builtin_amdgcn_cvt_pkrtz(vv[0], vv[1]);                 \
        pv2.hh[1] = __builtin_amdgcn_cvt_pkrtz(vv[2], vv[3]);                 \
        pv2.hh[2] = __builtin_amdgcn_cvt_pkrtz(vv[4], vv[5]);                 \
        pv2.hh[3] = __builtin_amdgcn_cvt_pkrtz(vv[6], vv[7]);                 \
        *(short8*)(Vt_s + hb + (bufv) * 2048 + wl * 512 + l * 8) = pv2.s;     \
    }

    // prologue: stage first tile into buf 0
    LOAD_TILE(kt_base);
    STORE_TILE(0);
    __syncthreads();

    for (int i = 0; i < 32; ++i) {
        const int kt = kt_base + i;
        const int cb = hb + (i & 1) * 2048;
        // issue next tile's global loads early (latency covered by compute)
        if (i < 31) LOAD_TILE(kt + 1);

        const u32 ml = mlw[kt * 64 + l];   // per-lane 16 mask bits, coalesced

        float pv[4][4];
#pragma unroll
        for (int t16 = 0; t16 < 4; ++t16) {
            const half8 kb = *(const half8*)(K_s + cb + (t16 * 4 + quad) * 128 + n16 * 8);
            float4v cc = {0.f, 0.f, 0.f, 0.f};
            cc = __builtin_amdgcn_mfma_f32_16x16x32_f16(qh, kb, cc, 0, 0, 0);
#pragma unroll
            for (int reg = 0; reg < 4; ++reg) {
                float e = EXP2(cc[reg]);
                pv[t16][reg] = (ml & (1u << (t16 * 4 + reg))) ? e : 0.f;
            }
        }
        // pack 4 t16-values per reg -> one b64 store at permuted positions
        // pos = n16*4 + t16  (P_perm[r][pos] = P[r][(pos&3)*16 + (pos>>2)])
#pragma unroll
        for (int reg = 0; reg < 4; ++reg) {
            fp16x2 h01 = __builtin_amdgcn_cvt_pkrtz(pv[0][reg], pv[1][reg]);
            fp16x2 h23 = __builtin_amdgcn_cvt_pkrtz(pv[2][reg], pv[3][reg]);
            union { fp16x2 hh[2]; short4v s; } pk;
            pk.hh[0] = h01; pk.hh[1] = h23;
            *(short4v*)(Ps + (quad * 4 + reg) * PS_STRIDE + n16 * 4) = pk.s;
        }
        // compiler fence: keep P stores ordered before P loads (same-wave)
        asm volatile("" ::: "memory");

#pragma unroll
        for (int khf = 0; khf < 2; ++khf) {
            const half8 pa = *(const half8*)(Ps + n16 * PS_STRIDE + khf * 32 + quad * 8);
            const half8 v0 = *(const half8*)(Vt_s + cb + ((khf * 2 + 0) * 4 + quad) * 128 + n16 * 8);
            const half8 v1 = *(const half8*)(Vt_s + cb + ((khf * 2 + 1) * 4 + quad) * 128 + n16 * 8);
            o0 = __builtin_amdgcn_mfma_f32_16x16x32_f16(pa, v0, o0, 0, 0, 0);
            o1 = __builtin_amdgcn_mfma_f32_16x16x32_f16(pa, v1, o1, 0, 0, 0);
            lacc = __builtin_amdgcn_mfma_f32_16x16x32_f16(pa, ones, lacc, 0, 0, 0);
        }

        // write next tile into the other buffer (it was fully consumed in
        // iter i-1; every wave passed the i-1 barrier) -> safe pre-barrier
        if (i < 31) STORE_TILE((i + 1) & 1);

        // single barrier: next-buf staged AND cur-buf reads done
        __syncthreads();
    }

    // ---- block-level combine: half 1 dumps partials, half 0 reduces+stores
    float* red = (float*)sm;            // reuse staging area (8.7KB < 32KB)
    const int RSTR = 16 * 33 + 16;      // per-wl region: o[16][33] + l[16]
    if (half == 1) {
        float* ro = red + wl * RSTR;
#pragma unroll
        for (int reg = 0; reg < 4; ++reg) {
            const int r = quad * 4 + reg;
            ro[r * 33 + n16]      = o0[reg];
            ro[r * 33 + 16 + n16] = o1[reg];
            if (n16 == 0) ro[16 * 33 + r] = lacc[reg];
        }
    }
    __syncthreads();
    if (half == 0) {
        const float* ro = red + wl * RSTR;
#pragma unroll
        for (int reg = 0; reg < 4; ++reg) {
            const int r = quad * 4 + reg;
            const float inv = 1.0f / (lacc[reg] + ro[16 * 33 + r]); // band => >0
            const int row = q0 + wl * 16 + r;
            float* orow = out + ((size_t)h * S_ + row) * D_;
            orow[n16]      = (o0[reg] + ro[r * 33 + n16]) * inv;
            orow[16 + n16] = (o1[reg] + ro[r * 33 + 16 + n16]) * inv;
        }
    }
#undef LOAD_TILE
#undef STORE_TILE
}

// ---------------- fallback fp32 kernel (proven) ----------------

#define QT 64
#define KT 64
#define NSUB 4
#define KPT 16

__global__ __launch_bounds__(256, 2)
void sparse_attn_fp32(const float* __restrict__ Q, const float* __restrict__ K,
                      const float* __restrict__ V, const int* __restrict__ mask,
                      float* __restrict__ out)
{
    __shared__ float Ks[KT][D_];
    __shared__ float Vs[KT][D_];
    __shared__ float red_o[NSUB][QT][D_ + 1];
    __shared__ float red_l[NSUB][QT];

    const int h = blockIdx.y;
    const int q0 = blockIdx.x * QT;
    const int tid = threadIdx.x;
    const int ql = tid & 63;
    const int sub = tid >> 6;
    const int q = q0 + ql;
    const float scale = 0.17677669529663687f;

    float4 qreg[8];
    const float4* qrow = (const float4*)(Q + ((size_t)h * S_ + q) * D_);
#pragma unroll
    for (int i = 0; i < 8; ++i) qreg[i] = qrow[i];

    float o[D_];
#pragma unroll
    for (int d = 0; d < D_; ++d) o[d] = 0.f;
    float lsum0 = 0.f;

    const float* Kh = K + (size_t)h * S_ * D_;
    const float* Vh = V + (size_t)h * S_ * D_;

    for (int jt = 0; jt < S_; jt += KT) {
        __syncthreads();
        {
            const float4* gK = (const float4*)(Kh + (size_t)jt * D_);
            const float4* gV = (const float4*)(Vh + (size_t)jt * D_);
            float4* sK = (float4*)&Ks[0][0];
            float4* sV = (float4*)&Vs[0][0];
            sK[tid] = gK[tid]; sK[tid + 256] = gK[tid + 256];
            sV[tid] = gV[tid]; sV[tid + 256] = gV[tid + 256];
        }
        __syncthreads();

        int4 m4[4];
        {
            const int4* mr = (const int4*)(mask + (size_t)q * S_ + jt + sub * KPT);
#pragma unroll
            for (int i = 0; i < 4; ++i) m4[i] = mr[i];
        }
        const int* mb = (const int*)m4;

#pragma unroll
        for (int kk = 0; kk < KPT; ++kk) {
            const int jl = sub * KPT + kk;
            const float4* krow = (const float4*)&Ks[jl][0];
            float s = 0.f;
#pragma unroll
            for (int i = 0; i < 8; ++i) {
                float4 kv = krow[i];
                s += qreg[i].x * kv.x + qreg[i].y * kv.y + qreg[i].z * kv.z + qreg[i].w * kv.w;
            }
            const float p = mb[kk] ? __expf(s * scale) : 0.f;
            lsum0 += p;
            const float4* vrow = (const float4*)&Vs[jl][0];
#pragma unroll
            for (int i = 0; i < 8; ++i) {
                float4 vv = vrow[i];
                o[i * 4 + 0] += p * vv.x;
                o[i * 4 + 1] += p * vv.y;
                o[i * 4 + 2] += p * vv.z;
                o[i * 4 + 3] += p * vv.w;
            }
        }
    }

#pragma unroll
    for (int d = 0; d < D_; ++d) red_o[sub][ql][d] = o[d];
    red_l[sub][ql] = lsum0;
    __syncthreads();

    const int eq = tid & 63;
    const int dg = tid >> 6;
    float acc[8];
#pragma unroll
    for (int i = 0; i < 8; ++i) acc[i] = 0.f;
    float lsum = 0.f;
#pragma unroll
    for (int s2 = 0; s2 < NSUB; ++s2) {
        lsum += red_l[s2][eq];
#pragma unroll
        for (int i = 0; i < 8; ++i) acc[i] += red_o[s2][eq][dg * 8 + i];
    }
    const float inv = 1.0f / lsum;
    float* orow = out + ((size_t)h * S_ + q0 + eq) * D_ + dg * 8;
#pragma unroll
    for (int i = 0; i < 8; ++i) orow[i] = acc[i] * inv;
}

// ---------------- host ----------------

extern "C" void kernel_launch(void* const* d_in, const int* in_sizes, int n_in,
                              void* d_out, int out_size, void* d_ws, size_t ws_size,
                              hipStream_t stream) {
    const float* Q = (const float*)d_in[0];
    const float* K = (const float*)d_in[1];
    const float* V = (const float*)d_in[2];
    const int* mask = (const int*)d_in[3];
    float* out = (float*)d_out;

    const size_t MB = 1024 * 1024;
    if (ws_size < 2 * MB) {
        dim3 grid(S_ / QT, H_);
        sparse_attn_fp32<<<grid, 256, 0, stream>>>(Q, K, V, mask, out);
        return;
    }

    ushort_t* mlane = (ushort_t*)d_ws;   // 2 MB

    prep_mask<<<1024, 256, 0, stream>>>(mask, mlane);

    dim3 grid(S_ / 64, H_);
    attn_mfma<<<grid, 512, 0, stream>>>(Q, K, V, mlane, out);
}